// Round 3
// baseline (374.309 us; speedup 1.0000x reference)
//
#include <hip/hip_runtime.h>
#include <hip/hip_bf16.h>

#define SEQ   2048
#define HD    128
#define BN    64
#define NITER (SEQ / BN)

typedef short bf16x8 __attribute__((ext_vector_type(8)));
typedef float f32x4  __attribute__((ext_vector_type(4)));

// pack two fp32 -> one uint holding (bf16(lo) | bf16(hi)<<16), RNE
__device__ __forceinline__ unsigned pk2(float lo, float hi) {
  float2 t; t.x = lo; t.y = hi;
  __hip_bfloat162 r = __float22bfloat162_rn(t);
  union { __hip_bfloat162 h; unsigned u; } cv; cv.h = r;
  return cv.u;
}

__global__ __launch_bounds__(256, 2)
void fa_gqa_kernel(const float* __restrict__ Q,
                   const float* __restrict__ K,
                   const float* __restrict__ V,
                   float* __restrict__ O)
{
  // K tile [64 krow][128 d] bf16, 16B chunk j stored at position j ^ (row&15)
  __shared__ unsigned short kt_lds[64 * HD];
  // V^T tile [128 d][64 k] bf16, 8-elem chunk kc8 stored at pos kc8 ^ (d&7) ^ (d>>4)
  __shared__ unsigned short vt_lds[HD * 64];
  // per-wave P [32 q][64 k] k-contiguous bf16, chunk kc8 at pos kc8 ^ (q&7)
  __shared__ unsigned short p_lds[4][32 * BN];

  const int tid  = threadIdx.x;
  const int lane = tid & 63;
  const int w    = tid >> 6;
  const int c    = lane & 15;   // MFMA "col" lane index
  const int qh   = lane >> 4;   // quad

  // XCD-clustered virtual block mapping (K/V L2 locality)
  const int F     = blockIdx.x;        // 0..1023
  const int xcd   = F & 7;
  const int s     = F >> 3;            // 0..127
  const int bh    = xcd * 8 + (s >> 4);
  const int qtile = s & 15;

  const int b = bh >> 5;
  const int h = bh & 31;
  const long qrow0 = (long)bh * SEQ + qtile * 128 + w * 32;
  const float* Qw = Q + qrow0 * HD;
  float*       Ow = O + qrow0 * HD;
  const long kvoff = (long)(b * 8 + (h >> 2)) * SEQ * HD;
  const float* Kb = K + kvoff;
  const float* Vb = V + kvoff;

  // Q fragments (B-operand: lane (c,qh) holds Q[q=qt*16+c][d=dc*32+qh*8+j])
  bf16x8 qf[2][4];
#pragma unroll
  for (int qt = 0; qt < 2; ++qt)
#pragma unroll
    for (int dc = 0; dc < 4; ++dc) {
      const float4* qp = (const float4*)(Qw + (qt * 16 + c) * HD + dc * 32 + qh * 8);
      float4 a = qp[0], bq = qp[1];
      int4 t;
      t.x = (int)pk2(a.x, a.y);
      t.y = (int)pk2(a.z, a.w);
      t.z = (int)pk2(bq.x, bq.y);
      t.w = (int)pk2(bq.z, bq.w);
      qf[qt][dc] = *(bf16x8*)&t;
    }

  f32x4 oacc[2][8];
#pragma unroll
  for (int mt = 0; mt < 2; ++mt)
#pragma unroll
    for (int nt = 0; nt < 8; ++nt)
      oacc[mt][nt] = (f32x4){0.f, 0.f, 0.f, 0.f};

  float mst[2] = {-1e30f, -1e30f};
  float lst[2] = {0.f, 0.f};

  const float K1 = 0.08838834764831845f * 1.4426950408889634f; // scale*log2(e)

  // staging roles
  const int krow = tid >> 2;      // K: 0..63
  const int kq4  = tid & 3;       // K: 32-float quarter of the row
  const int rp   = tid >> 3;      // V: row pair 0..31
  const int cc   = tid & 7;       // V: 16-float d chunk

  for (int it = 0; it < NITER; ++it) {
    const int k0 = it * BN;

    // global->VGPR fp32 loads for K and V (overlap barrier wait)
    const float4* kp = (const float4*)(Kb + (long)(k0 + krow) * HD + kq4 * 32);
    float4 kf[8];
#pragma unroll
    for (int i = 0; i < 8; ++i) kf[i] = kp[i];

    const float* vp = Vb + (long)(k0 + 2 * rp) * HD + cc * 16;
    float4 xr[4], yr[4];
#pragma unroll
    for (int i = 0; i < 4; ++i) {
      xr[i] = ((const float4*)vp)[i];
      yr[i] = ((const float4*)(vp + HD))[i];
    }

    __syncthreads();  // (A) all waves done reading prev K/V tiles

    // K staging: cvt to bf16, 4 swizzled b128 stores per thread
#pragma unroll
    for (int jj = 0; jj < 4; ++jj) {
      float4 e = kf[2 * jj], o = kf[2 * jj + 1];
      int4 wv;
      wv.x = (int)pk2(e.x, e.y);
      wv.y = (int)pk2(e.z, e.w);
      wv.z = (int)pk2(o.x, o.y);
      wv.w = (int)pk2(o.z, o.w);
      int j = kq4 * 4 + jj;
      int pos = j ^ (krow & 15);
      *(int4*)(kt_lds + krow * HD + pos * 8) = wv;
    }

    // V transpose: pack k row-pair per d into one b32
    {
      unsigned* vt32 = (unsigned*)vt_lds;
      const int kk = 2 * rp;
      const float* xf = (const float*)xr;
      const float* yf = (const float*)yr;
#pragma unroll
      for (int d = 0; d < 16; ++d) {
        unsigned wv = pk2(xf[d], yf[d]);
        int dd = 16 * cc + d;
        int wi = dd * 32 + (((kk >> 3) ^ (dd & 7) ^ (dd >> 4)) << 2) + ((kk & 7) >> 1);
        vt32[wi] = wv;
      }
    }

    __syncthreads();  // (B) staging visible

    // S^T = K * Q^T  (P^T lands k-contiguous per lane)
    f32x4 sacc[4][2];
#pragma unroll
    for (int kt = 0; kt < 4; ++kt)
#pragma unroll
      for (int qt = 0; qt < 2; ++qt)
        sacc[kt][qt] = (f32x4){0.f, 0.f, 0.f, 0.f};

#pragma unroll
    for (int dc = 0; dc < 4; ++dc) {
#pragma unroll
      for (int kt = 0; kt < 4; ++kt) {
        int row = kt * 16 + c;
        int pos = (4 * dc + qh) ^ c;
        bf16x8 af = *(const bf16x8*)(kt_lds + row * HD + pos * 8);
#pragma unroll
        for (int qt = 0; qt < 2; ++qt)
          sacc[kt][qt] = __builtin_amdgcn_mfma_f32_16x16x32_bf16(
              af, qf[qt][dc], sacc[kt][qt], 0, 0, 0);
      }
    }

    // online softmax per q-column (c); lane holds k = kt*16 + qh*4 + r
    float alpha[2];
#pragma unroll
    for (int qt = 0; qt < 2; ++qt) {
      float mx = sacc[0][qt][0];
#pragma unroll
      for (int kt = 0; kt < 4; ++kt)
#pragma unroll
        for (int r = 0; r < 4; ++r)
          mx = fmaxf(mx, sacc[kt][qt][r]);
      mx = fmaxf(mx, __shfl_xor(mx, 16, 64));
      mx = fmaxf(mx, __shfl_xor(mx, 32, 64));
      float mnew = fmaxf(mst[qt], mx);
      alpha[qt] = __builtin_amdgcn_exp2f(K1 * (mst[qt] - mnew));
      mst[qt] = mnew;
      float nm = -K1 * mnew;
      float sum = 0.f;
#pragma unroll
      for (int kt = 0; kt < 4; ++kt)
#pragma unroll
        for (int r = 0; r < 4; ++r) {
          float p = __builtin_amdgcn_exp2f(fmaf(sacc[kt][qt][r], K1, nm));
          sacc[kt][qt][r] = p;
          sum += p;
        }
      lst[qt] = lst[qt] * alpha[qt] + sum;  // quad-partial l
    }

    // write P (bf16) to per-wave LDS [q][k]
    unsigned short* pw = p_lds[w];
#pragma unroll
    for (int qt = 0; qt < 2; ++qt) {
      int qr = qt * 16 + c;
#pragma unroll
      for (int kt = 0; kt < 4; ++kt) {
        unsigned lo = pk2(sacc[kt][qt][0], sacc[kt][qt][1]);
        unsigned hi = pk2(sacc[kt][qt][2], sacc[kt][qt][3]);
        int kc8 = 2 * kt + (qh >> 1);
        int pos = kc8 ^ (qr & 7);
        *(uint2*)(pw + qr * BN + pos * 8 + (qh & 1) * 4) = make_uint2(lo, hi);
      }
    }

    // rescale O by alpha (broadcast q-col value to C-layout rows)
#pragma unroll
    for (int mt = 0; mt < 2; ++mt) {
#pragma unroll
      for (int r = 0; r < 4; ++r) {
        float av = __shfl(alpha[mt], 4 * qh + r, 64);
#pragma unroll
        for (int nt = 0; nt < 8; ++nt)
          oacc[mt][nt][r] *= av;
      }
    }

    __syncthreads();  // (C) P writes visible

    // O += P * V
#pragma unroll
    for (int kc = 0; kc < 2; ++kc) {
      bf16x8 pa[2];
#pragma unroll
      for (int mt = 0; mt < 2; ++mt) {
        int qr = mt * 16 + c;
        int pos = (4 * kc + qh) ^ (qr & 7);
        pa[mt] = *(const bf16x8*)(pw + qr * BN + pos * 8);
      }
#pragma unroll
      for (int nt = 0; nt < 8; ++nt) {
        int n = nt * 16 + c;
        int pos = (4 * kc + qh) ^ (n & 7) ^ (n >> 4);
        bf16x8 vb = *(const bf16x8*)(vt_lds + n * 64 + pos * 8);
#pragma unroll
        for (int mt = 0; mt < 2; ++mt)
          oacc[mt][nt] = __builtin_amdgcn_mfma_f32_16x16x32_bf16(
              pa[mt], vb, oacc[mt][nt], 0, 0, 0);
      }
    }
  }

  // epilogue: finish l reduction across quads, normalize, store fp32
  float linv[2];
#pragma unroll
  for (int qt = 0; qt < 2; ++qt) {
    float lf = lst[qt];
    lf += __shfl_xor(lf, 16, 64);
    lf += __shfl_xor(lf, 32, 64);
    linv[qt] = 1.0f / lf;
  }
#pragma unroll
  for (int mt = 0; mt < 2; ++mt) {
#pragma unroll
    for (int r = 0; r < 4; ++r) {
      float li = __shfl(linv[mt], 4 * qh + r, 64);
      float* orow = Ow + (mt * 16 + 4 * qh + r) * HD + c;
#pragma unroll
      for (int nt = 0; nt < 8; ++nt)
        orow[nt * 16] = oacc[mt][nt][r] * li;
    }
  }
}

extern "C" void kernel_launch(void* const* d_in, const int* in_sizes, int n_in,
                              void* d_out, int out_size, void* d_ws, size_t ws_size,
                              hipStream_t stream) {
  const float* q = (const float*)d_in[0];
  const float* k = (const float*)d_in[1];
  const float* v = (const float*)d_in[2];
  float* o = (float*)d_out;
  fa_gqa_kernel<<<dim3(1024), dim3(256), 0, stream>>>(q, k, v, o);
}